// Round 3
// baseline (19363.789 us; speedup 1.0000x reference)
//
#include <hip/hip_runtime.h>
#include <hip/hip_bf16.h>
#include <math.h>

// Problem constants (B=8, S=1024, D=768, DFF=3072, L=6, heads=4, hd=192)
#define TTOK 8192
#define DM   768
#define DQKV 2304
#define DFFN 3072
#define NBAT 8
#define NSEQ 1024
#define NHEAD 4
#define HDIM 192
#define NLAYER 6

static constexpr float ATT_SCALE = 0.07216878364870323f; // 1/sqrt(192)

__device__ __forceinline__ float gelu_exact(float z) {
    return 0.5f * z * (1.0f + erff(z * 0.70710678118654752f));
}

// ---------------------------------------------------------------------------
// C[M,N] = A[M,K] @ W[N,K]^T + bias[N]   (ACT=1: exact GELU epilogue)
// BM=BN=128, BK=16, 256 threads, 8x8 micro-tile. M,N multiples of 128; K of 16.
// ---------------------------------------------------------------------------
template <int ACT>
__global__ __launch_bounds__(256) void gemm_bias_kernel(
    const float* __restrict__ A, const float* __restrict__ W,
    const float* __restrict__ bias, float* __restrict__ C,
    int M, int N, int K)
{
    __shared__ float As[16][132];  // transposed A tile, padded (2-way-free writes)
    __shared__ float Ws[16][132];  // transposed W tile
    const int bn = blockIdx.x, bm = blockIdx.y;
    const int tid = threadIdx.x;
    const int tx = tid & 15, ty = tid >> 4;
    const int row0 = bm * 128, col0 = bn * 128;

    float acc[8][8];
#pragma unroll
    for (int i = 0; i < 8; i++)
#pragma unroll
        for (int j = 0; j < 8; j++) acc[i][j] = 0.0f;

    for (int k0 = 0; k0 < K; k0 += 16) {
#pragma unroll
        for (int i = 0; i < 2; i++) {
            const int f  = tid + i * 256;      // 0..511
            const int r  = f >> 2;             // 0..127
            const int kc = (f & 3) << 2;       // 0,4,8,12
            const float4 va = *(const float4*)&A[(size_t)(row0 + r) * K + k0 + kc];
            As[kc + 0][r] = va.x; As[kc + 1][r] = va.y;
            As[kc + 2][r] = va.z; As[kc + 3][r] = va.w;
            const float4 vw = *(const float4*)&W[(size_t)(col0 + r) * K + k0 + kc];
            Ws[kc + 0][r] = vw.x; Ws[kc + 1][r] = vw.y;
            Ws[kc + 2][r] = vw.z; Ws[kc + 3][r] = vw.w;
        }
        __syncthreads();
#pragma unroll
        for (int kk = 0; kk < 16; kk++) {
            const float4 a0 = *(const float4*)&As[kk][ty * 8];
            const float4 a1 = *(const float4*)&As[kk][ty * 8 + 4];
            const float4 b0 = *(const float4*)&Ws[kk][tx * 8];
            const float4 b1 = *(const float4*)&Ws[kk][tx * 8 + 4];
            const float av[8] = {a0.x, a0.y, a0.z, a0.w, a1.x, a1.y, a1.z, a1.w};
            const float bv[8] = {b0.x, b0.y, b0.z, b0.w, b1.x, b1.y, b1.z, b1.w};
#pragma unroll
            for (int ii = 0; ii < 8; ii++)
#pragma unroll
                for (int jj = 0; jj < 8; jj++)
                    acc[ii][jj] = fmaf(av[ii], bv[jj], acc[ii][jj]);
        }
        __syncthreads();
    }

    const float4 bb0 = *(const float4*)&bias[col0 + tx * 8];
    const float4 bb1 = *(const float4*)&bias[col0 + tx * 8 + 4];
    const float bv[8] = {bb0.x, bb0.y, bb0.z, bb0.w, bb1.x, bb1.y, bb1.z, bb1.w};
#pragma unroll
    for (int i = 0; i < 8; i++) {
        const int row = row0 + ty * 8 + i;
        float out[8];
#pragma unroll
        for (int j = 0; j < 8; j++) {
            float v = acc[i][j] + bv[j];
            if (ACT == 1) v = gelu_exact(v);
            out[j] = v;
        }
        float* cp = C + (size_t)row * N + col0 + tx * 8;
        *(float4*)cp       = make_float4(out[0], out[1], out[2], out[3]);
        *(float4*)(cp + 4) = make_float4(out[4], out[5], out[6], out[7]);
    }
}

// ---------------------------------------------------------------------------
// Local attention: per (s,h), 8-wide full attention over the batch dim.
// qkv layout [T,2304], out [T,768] (pre out-proj). Mask is all-allowed.
// ---------------------------------------------------------------------------
__global__ __launch_bounds__(256) void local_attn_kernel(
    const float* __restrict__ qkv, float* __restrict__ out)
{
    const int s = blockIdx.x, h = blockIdx.y;
    const int tid = threadIdx.x;
    __shared__ float qs[8][192], ks[8][192], vs[8][192];
    __shared__ float pr[8][8];

    for (int f = tid; f < 384; f += 256) {   // 8*48 float4 per matrix
        const int row = f / 48;
        const int c4  = (f % 48) * 4;
        const size_t t = (size_t)row * NSEQ + s;
        const float* base = qkv + t * DQKV + h * HDIM + c4;
        *(float4*)&qs[row][c4] = *(const float4*)(base);
        *(float4*)&ks[row][c4] = *(const float4*)(base + DM);
        *(float4*)&vs[row][c4] = *(const float4*)(base + 2 * DM);
    }
    __syncthreads();

    if (tid < 64) {
        const int i = tid >> 3, j = tid & 7;
        float sacc = 0.0f;
#pragma unroll
        for (int c = 0; c < 48; c++) {
            const float4 q = ((const float4*)qs[i])[c];
            const float4 k = ((const float4*)ks[j])[c];
            sacc += q.x * k.x + q.y * k.y + q.z * k.z + q.w * k.w;
        }
        sacc *= ATT_SCALE;
        float mx = sacc;
        mx = fmaxf(mx, __shfl_xor(mx, 1));
        mx = fmaxf(mx, __shfl_xor(mx, 2));
        mx = fmaxf(mx, __shfl_xor(mx, 4));
        float p = __expf(sacc - mx);
        float sum = p;
        sum += __shfl_xor(sum, 1);
        sum += __shfl_xor(sum, 2);
        sum += __shfl_xor(sum, 4);
        pr[i][j] = p / sum;
    }
    __syncthreads();

    for (int idx = tid; idx < 8 * HDIM; idx += 256) {
        const int i = idx / HDIM, d = idx % HDIM;
        float o = 0.0f;
#pragma unroll
        for (int j = 0; j < 8; j++) o = fmaf(pr[i][j], vs[j][d], o);
        const size_t t = (size_t)i * NSEQ + s;
        out[t * DM + h * HDIM + d] = o;
    }
}

// ---------------------------------------------------------------------------
// Global attention, flash-style. Grid (qt=32, h=4, b=8), 256 threads.
// Thread = (row r=tid>>3 of 32-row Q tile, 24-dim slice tx=tid&7).
// Q lives in registers; K/V tiles staged in LDS.
// ---------------------------------------------------------------------------
__global__ __launch_bounds__(256) void flash_attn_kernel(
    const float* __restrict__ qkv, float* __restrict__ out)
{
    const int qt = blockIdx.x, h = blockIdx.y, b = blockIdx.z;
    const int tid = threadIdx.x;
    const int r = tid >> 3, tx = tid & 7;
    __shared__ float ks[32][192];
    __shared__ float vs[32][192];

    float4 q4[6];
    {
        const size_t t = (size_t)b * NSEQ + qt * 32 + r;
        const float* qp = qkv + t * DQKV + h * HDIM + tx * 24;
#pragma unroll
        for (int c = 0; c < 6; c++) q4[c] = *(const float4*)(qp + c * 4);
    }
    float4 O4[6];
#pragma unroll
    for (int c = 0; c < 6; c++) O4[c] = make_float4(0.f, 0.f, 0.f, 0.f);
    float m = -INFINITY, l = 0.0f;

    for (int kt = 0; kt < 32; kt++) {
        __syncthreads();
#pragma unroll
        for (int i = 0; i < 6; i++) {
            const int f = tid + i * 256;      // 0..1535
            const int row = f / 48;
            const int c4  = (f % 48) * 4;
            const size_t t = (size_t)b * NSEQ + kt * 32 + row;
            const float* base = qkv + t * DQKV + h * HDIM + c4;
            *(float4*)&ks[row][c4] = *(const float4*)(base + DM);
            *(float4*)&vs[row][c4] = *(const float4*)(base + 2 * DM);
        }
        __syncthreads();

        float pj[32];
        float tm = -INFINITY;
#pragma unroll
        for (int j = 0; j < 32; j++) {
            float s = 0.0f;
            const float4* kp = (const float4*)&ks[j][tx * 24];
#pragma unroll
            for (int c = 0; c < 6; c++) {
                const float4 k4 = kp[c];
                s += q4[c].x * k4.x + q4[c].y * k4.y + q4[c].z * k4.z + q4[c].w * k4.w;
            }
            s += __shfl_xor(s, 1);
            s += __shfl_xor(s, 2);
            s += __shfl_xor(s, 4);
            s *= ATT_SCALE;
            pj[j] = s;
            tm = fmaxf(tm, s);
        }
        const float nm = fmaxf(m, tm);
        const float alpha = __expf(m - nm);
        float sl = 0.0f;
#pragma unroll
        for (int j = 0; j < 32; j++) { pj[j] = __expf(pj[j] - nm); sl += pj[j]; }
        l = l * alpha + sl;
        m = nm;
#pragma unroll
        for (int c = 0; c < 6; c++) {
            O4[c].x *= alpha; O4[c].y *= alpha; O4[c].z *= alpha; O4[c].w *= alpha;
        }
#pragma unroll
        for (int j = 0; j < 32; j++) {
            const float p = pj[j];
            const float4* vp = (const float4*)&vs[j][tx * 24];
#pragma unroll
            for (int c = 0; c < 6; c++) {
                const float4 v4 = vp[c];
                O4[c].x = fmaf(p, v4.x, O4[c].x);
                O4[c].y = fmaf(p, v4.y, O4[c].y);
                O4[c].z = fmaf(p, v4.z, O4[c].z);
                O4[c].w = fmaf(p, v4.w, O4[c].w);
            }
        }
    }
    const float inv = 1.0f / l;
    const size_t t = (size_t)b * NSEQ + qt * 32 + r;
    float* op = out + t * DM + h * HDIM + tx * 24;
#pragma unroll
    for (int c = 0; c < 6; c++) {
        *(float4*)(op + c * 4) =
            make_float4(O4[c].x * inv, O4[c].y * inv, O4[c].z * inv, O4[c].w * inv);
    }
}

// ---------------------------------------------------------------------------
// Fused adds + LayerNorm. One block per row (768 cols, 256 threads x 3).
// ---------------------------------------------------------------------------
__device__ __forceinline__ float block_sum(float val, float* sbuf) {
#pragma unroll
    for (int off = 32; off > 0; off >>= 1) val += __shfl_down(val, off);
    const int w = threadIdx.x >> 6;
    if ((threadIdx.x & 63) == 0) sbuf[w] = val;
    __syncthreads();
    const float r = sbuf[0] + sbuf[1] + sbuf[2] + sbuf[3];
    __syncthreads();
    return r;
}

// out = LN(x + a + b) * g + beta
__global__ __launch_bounds__(256) void add_ln_kernel(
    const float* __restrict__ x, const float* __restrict__ a,
    const float* __restrict__ b, const float* __restrict__ g,
    const float* __restrict__ beta, float* __restrict__ out)
{
    __shared__ float sbuf[4];
    const size_t row = blockIdx.x;
    const int tid = threadIdx.x;
    const float* xr = x + row * DM;
    const float* ar = a + row * DM;
    const float* br = b + row * DM;
    float v[3];
    float lsum = 0.0f;
#pragma unroll
    for (int i = 0; i < 3; i++) {
        const int d = tid + i * 256;
        v[i] = xr[d] + ar[d] + br[d];
        lsum += v[i];
    }
    const float mean = block_sum(lsum, sbuf) * (1.0f / DM);
    float vsum = 0.0f;
#pragma unroll
    for (int i = 0; i < 3; i++) { const float t = v[i] - mean; vsum += t * t; }
    const float rstd = rsqrtf(block_sum(vsum, sbuf) * (1.0f / DM) + 1e-5f);
    float* orow = out + row * DM;
#pragma unroll
    for (int i = 0; i < 3; i++) {
        const int d = tid + i * 256;
        orow[d] = (v[i] - mean) * rstd * g[d] + beta[d];
    }
}

// xio = gamma * LN(x1 + h) * g + beta ... + xio   (residual in-place)
__global__ __launch_bounds__(256) void add_ln_res_kernel(
    const float* __restrict__ x1, const float* __restrict__ hbuf,
    const float* __restrict__ g, const float* __restrict__ beta,
    const float* __restrict__ gamma_ptr, float* __restrict__ xio)
{
    __shared__ float sbuf[4];
    const size_t row = blockIdx.x;
    const int tid = threadIdx.x;
    const float gamma = *gamma_ptr;
    const float* xr = x1 + row * DM;
    const float* hr = hbuf + row * DM;
    float v[3];
    float lsum = 0.0f;
#pragma unroll
    for (int i = 0; i < 3; i++) {
        const int d = tid + i * 256;
        v[i] = xr[d] + hr[d];
        lsum += v[i];
    }
    const float mean = block_sum(lsum, sbuf) * (1.0f / DM);
    float vsum = 0.0f;
#pragma unroll
    for (int i = 0; i < 3; i++) { const float t = v[i] - mean; vsum += t * t; }
    const float rstd = rsqrtf(block_sum(vsum, sbuf) * (1.0f / DM) + 1e-5f);
    float* orow = xio + row * DM;
#pragma unroll
    for (int i = 0; i < 3; i++) {
        const int d = tid + i * 256;
        const float xn = (v[i] - mean) * rstd * g[d] + beta[d];
        orow[d] = fmaf(gamma, xn, orow[d]);
    }
}

// ---------------------------------------------------------------------------
extern "C" void kernel_launch(void* const* d_in, const int* in_sizes, int n_in,
                              void* d_out, int out_size, void* d_ws, size_t ws_size,
                              hipStream_t stream)
{
    const float* x_in   = (const float*)d_in[0];
    const float* lin_w  = (const float*)d_in[1];
    const float* lin_b  = (const float*)d_in[2];
    const float* lout_w = (const float*)d_in[3];
    const float* lout_b = (const float*)d_in[4];
    const float* gin_w  = (const float*)d_in[5];
    const float* gin_b  = (const float*)d_in[6];
    const float* gout_w = (const float*)d_in[7];
    const float* gout_b = (const float*)d_in[8];
    const float* ffw1   = (const float*)d_in[9];
    const float* ffb1   = (const float*)d_in[10];
    const float* ffw2   = (const float*)d_in[11];
    const float* ffb2   = (const float*)d_in[12];
    const float* ln1g   = (const float*)d_in[13];
    const float* ln1b   = (const float*)d_in[14];
    const float* ln2g   = (const float*)d_in[15];
    const float* ln2b   = (const float*)d_in[16];
    const float* gammas = (const float*)d_in[17];

    const size_t NT = (size_t)TTOK * DM;           // 6,291,456
    float* ws   = (float*)d_ws;
    float* x1   = ws;                               // [T,D]
    float* labf = ws + NT;                          // [T,D]  la / later h2
    float* gabf = ws + 2 * NT;                      // [T,D]
    float* pre  = ws + 3 * NT;                      // [T,D]  attn pre-proj
    float* big  = ws + 4 * NT;                      // [T,3072] qkv / h1
    float* xbuf = (float*)d_out;                    // persistent x (also output)

    hipMemcpyAsync(xbuf, x_in, NT * sizeof(float), hipMemcpyDeviceToDevice, stream);

    const dim3 blk(256);
    const dim3 g_qkv(DQKV / 128, TTOK / 128);
    const dim3 g_prj(DM / 128, TTOK / 128);
    const dim3 g_ff1(DFFN / 128, TTOK / 128);
    const dim3 g_lcl(NSEQ, NHEAD);
    const dim3 g_fla(NSEQ / 32, NHEAD, NBAT);

    for (int i = 0; i < NLAYER; i++) {
        const float* Wli = lin_w  + (size_t)i * DQKV * DM;
        const float* bli = lin_b  + (size_t)i * DQKV;
        const float* Wlo = lout_w + (size_t)i * DM * DM;
        const float* blo = lout_b + (size_t)i * DM;
        const float* Wgi = gin_w  + (size_t)i * DQKV * DM;
        const float* bgi = gin_b  + (size_t)i * DQKV;
        const float* Wgo = gout_w + (size_t)i * DM * DM;
        const float* bgo = gout_b + (size_t)i * DM;
        const float* W1  = ffw1   + (size_t)i * DFFN * DM;
        const float* b1  = ffb1   + (size_t)i * DFFN;
        const float* W2  = ffw2   + (size_t)i * DM * DFFN;
        const float* b2  = ffb2   + (size_t)i * DM;
        const float* g1  = ln1g + (size_t)i * DM;
        const float* be1 = ln1b + (size_t)i * DM;
        const float* g2  = ln2g + (size_t)i * DM;
        const float* be2 = ln2b + (size_t)i * DM;

        // local branch
        gemm_bias_kernel<0><<<g_qkv, blk, 0, stream>>>(xbuf, Wli, bli, big, TTOK, DQKV, DM);
        local_attn_kernel<<<g_lcl, blk, 0, stream>>>(big, pre);
        gemm_bias_kernel<0><<<g_prj, blk, 0, stream>>>(pre, Wlo, blo, labf, TTOK, DM, DM);
        // global branch
        gemm_bias_kernel<0><<<g_qkv, blk, 0, stream>>>(xbuf, Wgi, bgi, big, TTOK, DQKV, DM);
        flash_attn_kernel<<<g_fla, blk, 0, stream>>>(big, pre);
        gemm_bias_kernel<0><<<g_prj, blk, 0, stream>>>(pre, Wgo, bgo, gabf, TTOK, DM, DM);
        // x1 = LN1(x + la + ga)
        add_ln_kernel<<<TTOK, blk, 0, stream>>>(xbuf, labf, gabf, g1, be1, x1);
        // FFN
        gemm_bias_kernel<1><<<g_ff1, blk, 0, stream>>>(x1, W1, b1, big, TTOK, DFFN, DM);
        gemm_bias_kernel<0><<<g_prj, blk, 0, stream>>>(big, W2, b2, labf, TTOK, DM, DFFN);
        // x = gamma * LN2(x1 + h) + x   (residual == layer input x)
        add_ln_res_kernel<<<TTOK, blk, 0, stream>>>(x1, labf, g2, be2, gammas + i, xbuf);
    }
}

// Round 4
// 7568.202 us; speedup vs baseline: 2.5586x; 2.5586x over previous
//
#include <hip/hip_runtime.h>
#include <hip/hip_bf16.h>
#include <math.h>

// Problem constants (B=8, S=1024, D=768, DFF=3072, L=6, heads=4, hd=192)
#define TTOK 8192
#define DM   768
#define DQKV 2304
#define DFFN 3072
#define NBAT 8
#define NSEQ 1024
#define NHEAD 4
#define HDIM 192
#define NLAYER 6

static constexpr float ATT_SCALE = 0.07216878364870323f; // 1/sqrt(192)

typedef __attribute__((ext_vector_type(8))) short bf16x8;  // 8 bf16 in 4 VGPRs
typedef __attribute__((ext_vector_type(4))) float f32x4;

__device__ __forceinline__ float gelu_exact(float z) {
    return 0.5f * z * (1.0f + erff(z * 0.70710678118654752f));
}

// pack two fp32 into two bf16 (RNE via __bf16 cast -> compiler emits v_cvt_pk_bf16_f32)
__device__ __forceinline__ unsigned int pack_bf16_2(float lo, float hi) {
    __bf16 a = (__bf16)lo, b = (__bf16)hi;
    unsigned short ua = __builtin_bit_cast(unsigned short, a);
    unsigned short ub = __builtin_bit_cast(unsigned short, b);
    return (unsigned int)ua | ((unsigned int)ub << 16);
}

// ---------------------------------------------------------------------------
// MFMA GEMM: C[M,N] = A[M,K](fp32) @ W[N,K](fp32)^T + bias, bf16 compute.
// BM=BN=128, BK=32, 256 thr = 4 waves (2x2), wave does 64x64 via 4x4 frags of
// 16x16x32. LDS row stride 40 bf16 (80B) -> 2-way-only bank aliasing (free).
// ---------------------------------------------------------------------------
template <int ACT>
__global__ __launch_bounds__(256) void gemm_mfma_kernel(
    const float* __restrict__ A, const float* __restrict__ W,
    const float* __restrict__ bias, float* __restrict__ C,
    int M, int N, int K)
{
    __shared__ unsigned short As[128 * 40];
    __shared__ unsigned short Ws[128 * 40];
    const int tid  = threadIdx.x;
    const int lane = tid & 63;
    const int wid  = tid >> 6;          // 0..3
    const int wr   = wid >> 1;          // wave row (2)
    const int wc   = wid & 1;           // wave col (2)
    const int row0 = blockIdx.y * 128, col0 = blockIdx.x * 128;

    const int srow = tid >> 3;          // 0..31 staging row base
    const int sk4  = (tid & 7) * 4;     // k-offset 0,4,...,28

    f32x4 acc[4][4];
#pragma unroll
    for (int m = 0; m < 4; m++)
#pragma unroll
        for (int n = 0; n < 4; n++)
            acc[m][n] = (f32x4){0.f, 0.f, 0.f, 0.f};

    const int fr  = lane & 15;          // fragment row within 16
    const int kg  = lane >> 4;          // k-group 0..3 (8 elems each)

    for (int k0 = 0; k0 < K; k0 += 32) {
        __syncthreads();
#pragma unroll
        for (int i = 0; i < 4; i++) {
            const int r = srow + i * 32;
            const float4 va = *(const float4*)&A[(size_t)(row0 + r) * K + k0 + sk4];
            uint2 pa;
            pa.x = pack_bf16_2(va.x, va.y);
            pa.y = pack_bf16_2(va.z, va.w);
            *(uint2*)&As[r * 40 + sk4] = pa;
            const float4 vw = *(const float4*)&W[(size_t)(col0 + r) * K + k0 + sk4];
            uint2 pw;
            pw.x = pack_bf16_2(vw.x, vw.y);
            pw.y = pack_bf16_2(vw.z, vw.w);
            *(uint2*)&Ws[r * 40 + sk4] = pw;
        }
        __syncthreads();

        bf16x8 af[4], bfr[4];
#pragma unroll
        for (int m = 0; m < 4; m++) {
            const int row = wr * 64 + m * 16 + fr;
            af[m] = *(const bf16x8*)&As[row * 40 + kg * 8];
        }
#pragma unroll
        for (int n = 0; n < 4; n++) {
            const int row = wc * 64 + n * 16 + fr;
            bfr[n] = *(const bf16x8*)&Ws[row * 40 + kg * 8];
        }
#pragma unroll
        for (int m = 0; m < 4; m++)
#pragma unroll
            for (int n = 0; n < 4; n++)
                acc[m][n] = __builtin_amdgcn_mfma_f32_16x16x32_bf16(
                    af[m], bfr[n], acc[m][n], 0, 0, 0);
    }

    // Epilogue. C/D layout: col = lane&15, row = (lane>>4)*4 + reg  [m89-verified]
#pragma unroll
    for (int n = 0; n < 4; n++) {
        const int col = col0 + wc * 64 + n * 16 + fr;
        const float bv = bias[col];
#pragma unroll
        for (int m = 0; m < 4; m++) {
#pragma unroll
            for (int j = 0; j < 4; j++) {
                const int row = row0 + wr * 64 + m * 16 + kg * 4 + j;
                float v = acc[m][n][j] + bv;
                if (ACT == 1) v = gelu_exact(v);
                C[(size_t)row * N + col] = v;
            }
        }
    }
}

// ---------------------------------------------------------------------------
// Local attention: per (s,h), 8-wide full attention over the batch dim.
// ---------------------------------------------------------------------------
__global__ __launch_bounds__(256) void local_attn_kernel(
    const float* __restrict__ qkv, float* __restrict__ out)
{
    const int s = blockIdx.x, h = blockIdx.y;
    const int tid = threadIdx.x;
    __shared__ float qs[8][192], ks[8][192], vs[8][192];
    __shared__ float pr[8][8];

    for (int f = tid; f < 384; f += 256) {
        const int row = f / 48;
        const int c4  = (f % 48) * 4;
        const size_t t = (size_t)row * NSEQ + s;
        const float* base = qkv + t * DQKV + h * HDIM + c4;
        *(float4*)&qs[row][c4] = *(const float4*)(base);
        *(float4*)&ks[row][c4] = *(const float4*)(base + DM);
        *(float4*)&vs[row][c4] = *(const float4*)(base + 2 * DM);
    }
    __syncthreads();

    if (tid < 64) {
        const int i = tid >> 3, j = tid & 7;
        float sacc = 0.0f;
#pragma unroll
        for (int c = 0; c < 48; c++) {
            const float4 q = ((const float4*)qs[i])[c];
            const float4 k = ((const float4*)ks[j])[c];
            sacc += q.x * k.x + q.y * k.y + q.z * k.z + q.w * k.w;
        }
        sacc *= ATT_SCALE;
        float mx = sacc;
        mx = fmaxf(mx, __shfl_xor(mx, 1));
        mx = fmaxf(mx, __shfl_xor(mx, 2));
        mx = fmaxf(mx, __shfl_xor(mx, 4));
        float p = __expf(sacc - mx);
        float sum = p;
        sum += __shfl_xor(sum, 1);
        sum += __shfl_xor(sum, 2);
        sum += __shfl_xor(sum, 4);
        pr[i][j] = p / sum;
    }
    __syncthreads();

    for (int idx = tid; idx < 8 * HDIM; idx += 256) {
        const int i = idx / HDIM, d = idx % HDIM;
        float o = 0.0f;
#pragma unroll
        for (int j = 0; j < 8; j++) o = fmaf(pr[i][j], vs[j][d], o);
        const size_t t = (size_t)i * NSEQ + s;
        out[t * DM + h * HDIM + d] = o;
    }
}

// ---------------------------------------------------------------------------
// Global attention v2 (shuffle-light tiled flash).
// Block: 256 thr, 32 q-rows, loop 64 K/V tiles of 16 keys.
// QK phase: thread (ty,tx) = (rows {ty,ty+16}, key tx). Row stats via 4
// shfl_xor within 16-lane groups. PV phase: thread = (rows {ty,ty+16},
// 12-dim slice tx). P through LDS.
// ---------------------------------------------------------------------------
__global__ __launch_bounds__(256) void flash2_kernel(
    const float* __restrict__ qkv, float* __restrict__ out)
{
    const int qt = blockIdx.x;   // 0..31
    const int h  = blockIdx.y;   // 0..3
    const int b  = blockIdx.z;   // 0..7
    const int tid = threadIdx.x;
    const int ty = tid >> 4;     // 0..15
    const int tx = tid & 15;     // 0..15

    __shared__ float Qs[32][196];
    __shared__ float Ks[16][196];
    __shared__ float Vs[16][196];
    __shared__ float Ps[32][17];

    // stage Q tile once (32 x 192)
    for (int f = tid; f < 1536; f += 256) {
        const int row = f / 48, c4 = (f % 48) * 4;
        const size_t t = (size_t)b * NSEQ + qt * 32 + row;
        *(float4*)&Qs[row][c4] = *(const float4*)&qkv[t * DQKV + h * HDIM + c4];
    }

    float4 O0[3], O1[3];
#pragma unroll
    for (int d = 0; d < 3; d++) {
        O0[d] = make_float4(0.f, 0.f, 0.f, 0.f);
        O1[d] = make_float4(0.f, 0.f, 0.f, 0.f);
    }
    float mA = -INFINITY, mB = -INFINITY, lA = 0.f, lB = 0.f;

    for (int kt = 0; kt < 64; kt++) {
        __syncthreads();
        for (int f = tid; f < 768; f += 256) {
            const int row = f / 48, c4 = (f % 48) * 4;
            const size_t t = (size_t)b * NSEQ + kt * 16 + row;
            const float* base = &qkv[t * DQKV + h * HDIM + c4];
            *(float4*)&Ks[row][c4] = *(const float4*)(base + DM);
            *(float4*)&Vs[row][c4] = *(const float4*)(base + 2 * DM);
        }
        __syncthreads();

        // scores for rows ty and ty+16 vs key tx
        float sA = 0.f, sB = 0.f;
#pragma unroll 16
        for (int c = 0; c < 48; c++) {
            const float4 k4 = *(const float4*)&Ks[tx][c * 4];
            const float4 qa = *(const float4*)&Qs[ty][c * 4];
            const float4 qb = *(const float4*)&Qs[ty + 16][c * 4];
            sA += qa.x * k4.x + qa.y * k4.y + qa.z * k4.z + qa.w * k4.w;
            sB += qb.x * k4.x + qb.y * k4.y + qb.z * k4.z + qb.w * k4.w;
        }
        sA *= ATT_SCALE; sB *= ATT_SCALE;

        // row max over the 16 tx lanes
        float tmA = sA, tmB = sB;
#pragma unroll
        for (int off = 1; off < 16; off <<= 1) {
            tmA = fmaxf(tmA, __shfl_xor(tmA, off));
            tmB = fmaxf(tmB, __shfl_xor(tmB, off));
        }
        const float nmA = fmaxf(mA, tmA), nmB = fmaxf(mB, tmB);
        const float pA = __expf(sA - nmA), pB = __expf(sB - nmB);
        float slA = pA, slB = pB;
#pragma unroll
        for (int off = 1; off < 16; off <<= 1) {
            slA += __shfl_xor(slA, off);
            slB += __shfl_xor(slB, off);
        }
        const float alA = __expf(mA - nmA), alB = __expf(mB - nmB);
        lA = lA * alA + slA; mA = nmA;
        lB = lB * alB + slB; mB = nmB;
        Ps[ty][tx]      = pA;
        Ps[ty + 16][tx] = pB;
#pragma unroll
        for (int d = 0; d < 3; d++) {
            O0[d].x *= alA; O0[d].y *= alA; O0[d].z *= alA; O0[d].w *= alA;
            O1[d].x *= alB; O1[d].y *= alB; O1[d].z *= alB; O1[d].w *= alB;
        }
        __syncthreads();   // P visible

        // PV: rows {ty, ty+16}, dims [tx*12, tx*12+12)
#pragma unroll
        for (int j = 0; j < 16; j++) {
            const float pa = Ps[ty][j];
            const float pb = Ps[ty + 16][j];
#pragma unroll
            for (int d = 0; d < 3; d++) {
                const float4 v4 = *(const float4*)&Vs[j][tx * 12 + d * 4];
                O0[d].x = fmaf(pa, v4.x, O0[d].x);
                O0[d].y = fmaf(pa, v4.y, O0[d].y);
                O0[d].z = fmaf(pa, v4.z, O0[d].z);
                O0[d].w = fmaf(pa, v4.w, O0[d].w);
                O1[d].x = fmaf(pb, v4.x, O1[d].x);
                O1[d].y = fmaf(pb, v4.y, O1[d].y);
                O1[d].z = fmaf(pb, v4.z, O1[d].z);
                O1[d].w = fmaf(pb, v4.w, O1[d].w);
            }
        }
    }

    const float ivA = 1.0f / lA, ivB = 1.0f / lB;
    const size_t tA = (size_t)b * NSEQ + qt * 32 + ty;
    const size_t tB = tA + 16;
#pragma unroll
    for (int d = 0; d < 3; d++) {
        *(float4*)&out[tA * DM + h * HDIM + tx * 12 + d * 4] =
            make_float4(O0[d].x * ivA, O0[d].y * ivA, O0[d].z * ivA, O0[d].w * ivA);
        *(float4*)&out[tB * DM + h * HDIM + tx * 12 + d * 4] =
            make_float4(O1[d].x * ivB, O1[d].y * ivB, O1[d].z * ivB, O1[d].w * ivB);
    }
}

// ---------------------------------------------------------------------------
// Fused adds + LayerNorm. One block per row (768 cols, 256 threads x 3).
// ---------------------------------------------------------------------------
__device__ __forceinline__ float block_sum(float val, float* sbuf) {
#pragma unroll
    for (int off = 32; off > 0; off >>= 1) val += __shfl_down(val, off);
    const int w = threadIdx.x >> 6;
    if ((threadIdx.x & 63) == 0) sbuf[w] = val;
    __syncthreads();
    const float r = sbuf[0] + sbuf[1] + sbuf[2] + sbuf[3];
    __syncthreads();
    return r;
}

__global__ __launch_bounds__(256) void add_ln_kernel(
    const float* __restrict__ x, const float* __restrict__ a,
    const float* __restrict__ b, const float* __restrict__ g,
    const float* __restrict__ beta, float* __restrict__ out)
{
    __shared__ float sbuf[4];
    const size_t row = blockIdx.x;
    const int tid = threadIdx.x;
    const float* xr = x + row * DM;
    const float* ar = a + row * DM;
    const float* br = b + row * DM;
    float v[3];
    float lsum = 0.0f;
#pragma unroll
    for (int i = 0; i < 3; i++) {
        const int d = tid + i * 256;
        v[i] = xr[d] + ar[d] + br[d];
        lsum += v[i];
    }
    const float mean = block_sum(lsum, sbuf) * (1.0f / DM);
    float vsum = 0.0f;
#pragma unroll
    for (int i = 0; i < 3; i++) { const float t = v[i] - mean; vsum += t * t; }
    const float rstd = rsqrtf(block_sum(vsum, sbuf) * (1.0f / DM) + 1e-5f);
    float* orow = out + row * DM;
#pragma unroll
    for (int i = 0; i < 3; i++) {
        const int d = tid + i * 256;
        orow[d] = (v[i] - mean) * rstd * g[d] + beta[d];
    }
}

__global__ __launch_bounds__(256) void add_ln_res_kernel(
    const float* __restrict__ x1, const float* __restrict__ hbuf,
    const float* __restrict__ g, const float* __restrict__ beta,
    const float* __restrict__ gamma_ptr, float* __restrict__ xio)
{
    __shared__ float sbuf[4];
    const size_t row = blockIdx.x;
    const int tid = threadIdx.x;
    const float gamma = *gamma_ptr;
    const float* xr = x1 + row * DM;
    const float* hr = hbuf + row * DM;
    float v[3];
    float lsum = 0.0f;
#pragma unroll
    for (int i = 0; i < 3; i++) {
        const int d = tid + i * 256;
        v[i] = xr[d] + hr[d];
        lsum += v[i];
    }
    const float mean = block_sum(lsum, sbuf) * (1.0f / DM);
    float vsum = 0.0f;
#pragma unroll
    for (int i = 0; i < 3; i++) { const float t = v[i] - mean; vsum += t * t; }
    const float rstd = rsqrtf(block_sum(vsum, sbuf) * (1.0f / DM) + 1e-5f);
    float* orow = xio + row * DM;
#pragma unroll
    for (int i = 0; i < 3; i++) {
        const int d = tid + i * 256;
        const float xn = (v[i] - mean) * rstd * g[d] + beta[d];
        orow[d] = fmaf(gamma, xn, orow[d]);
    }
}

// ---------------------------------------------------------------------------
extern "C" void kernel_launch(void* const* d_in, const int* in_sizes, int n_in,
                              void* d_out, int out_size, void* d_ws, size_t ws_size,
                              hipStream_t stream)
{
    const float* x_in   = (const float*)d_in[0];
    const float* lin_w  = (const float*)d_in[1];
    const float* lin_b  = (const float*)d_in[2];
    const float* lout_w = (const float*)d_in[3];
    const float* lout_b = (const float*)d_in[4];
    const float* gin_w  = (const float*)d_in[5];
    const float* gin_b  = (const float*)d_in[6];
    const float* gout_w = (const float*)d_in[7];
    const float* gout_b = (const float*)d_in[8];
    const float* ffw1   = (const float*)d_in[9];
    const float* ffb1   = (const float*)d_in[10];
    const float* ffw2   = (const float*)d_in[11];
    const float* ffb2   = (const float*)d_in[12];
    const float* ln1g   = (const float*)d_in[13];
    const float* ln1b   = (const float*)d_in[14];
    const float* ln2g   = (const float*)d_in[15];
    const float* ln2b   = (const float*)d_in[16];
    const float* gammas = (const float*)d_in[17];

    const size_t NT = (size_t)TTOK * DM;
    float* ws   = (float*)d_ws;
    float* x1   = ws;
    float* labf = ws + NT;
    float* gabf = ws + 2 * NT;
    float* pre  = ws + 3 * NT;
    float* big  = ws + 4 * NT;          // [T,3072]
    float* xbuf = (float*)d_out;

    hipMemcpyAsync(xbuf, x_in, NT * sizeof(float), hipMemcpyDeviceToDevice, stream);

    const dim3 blk(256);
    const dim3 g_qkv(DQKV / 128, TTOK / 128);
    const dim3 g_prj(DM / 128, TTOK / 128);
    const dim3 g_ff1(DFFN / 128, TTOK / 128);
    const dim3 g_lcl(NSEQ, NHEAD);
    const dim3 g_fla(NSEQ / 32, NHEAD, NBAT);

    for (int i = 0; i < NLAYER; i++) {
        const float* Wli = lin_w  + (size_t)i * DQKV * DM;
        const float* bli = lin_b  + (size_t)i * DQKV;
        const float* Wlo = lout_w + (size_t)i * DM * DM;
        const float* blo = lout_b + (size_t)i * DM;
        const float* Wgi = gin_w  + (size_t)i * DQKV * DM;
        const float* bgi = gin_b  + (size_t)i * DQKV;
        const float* Wgo = gout_w + (size_t)i * DM * DM;
        const float* bgo = gout_b + (size_t)i * DM;
        const float* W1  = ffw1   + (size_t)i * DFFN * DM;
        const float* b1  = ffb1   + (size_t)i * DFFN;
        const float* W2  = ffw2   + (size_t)i * DM * DFFN;
        const float* b2  = ffb2   + (size_t)i * DM;
        const float* g1  = ln1g + (size_t)i * DM;
        const float* be1 = ln1b + (size_t)i * DM;
        const float* g2  = ln2g + (size_t)i * DM;
        const float* be2 = ln2b + (size_t)i * DM;

        // local branch
        gemm_mfma_kernel<0><<<g_qkv, blk, 0, stream>>>(xbuf, Wli, bli, big, TTOK, DQKV, DM);
        local_attn_kernel<<<g_lcl, blk, 0, stream>>>(big, pre);
        gemm_mfma_kernel<0><<<g_prj, blk, 0, stream>>>(pre, Wlo, blo, labf, TTOK, DM, DM);
        // global branch
        gemm_mfma_kernel<0><<<g_qkv, blk, 0, stream>>>(xbuf, Wgi, bgi, big, TTOK, DQKV, DM);
        flash2_kernel<<<g_fla, blk, 0, stream>>>(big, pre);
        gemm_mfma_kernel<0><<<g_prj, blk, 0, stream>>>(pre, Wgo, bgo, gabf, TTOK, DM, DM);
        // x1 = LN1(x + la + ga)
        add_ln_kernel<<<TTOK, blk, 0, stream>>>(xbuf, labf, gabf, g1, be1, x1);
        // FFN
        gemm_mfma_kernel<1><<<g_ff1, blk, 0, stream>>>(x1, W1, b1, big, TTOK, DFFN, DM);
        gemm_mfma_kernel<0><<<g_prj, blk, 0, stream>>>(big, W2, b2, labf, TTOK, DM, DFFN);
        // x = gamma * LN2(x1 + h) + x
        add_ln_res_kernel<<<TTOK, blk, 0, stream>>>(x1, labf, g2, be2, gammas + i, xbuf);
    }
}